// Round 6
// baseline (347.445 us; speedup 1.0000x reference)
//
#include <hip/hip_runtime.h>
#include <hip/hip_bf16.h>
#include <math.h>

#define NHEAD 8
#define CDIM 16
#define HCDIM 128
#define NGRAPH 64
#define WEXT 144   // 128 gemm cols + 8 src-coeff cols + 8 dst-coeff cols
#define SWPAD 136  // +8 shorts pad: row stride 68 dwords == 4 mod 32 banks

typedef __attribute__((ext_vector_type(8))) short short8;
typedef __attribute__((ext_vector_type(4))) float f32x4;
typedef __attribute__((ext_vector_type(2))) float f32x2;

static __device__ __forceinline__ unsigned short f2bf(float f) {
    unsigned u = __float_as_uint(f);
    unsigned r = (u + 0x7FFF + ((u >> 16) & 1)) >> 16;   // rne
    return (unsigned short)r;
}
static __device__ __forceinline__ float bf2f(unsigned short s) {
    return __uint_as_float(((unsigned)s) << 16);
}
// unpack a bf16x2 dword into {lo, hi} floats (feeds v_pk_fma_f32)
static __device__ __forceinline__ f32x2 bfpair(unsigned u) {
    return (f32x2){ __uint_as_float(u << 16), __uint_as_float(u & 0xffff0000u) };
}

// ---------------------------------------------------------------- setup

// merged: zero deg/gsum + kcoef + graph_bounds + extended weight build (bf16)
// + layer-1 coeff tables was1/wad1 [4][8]
__global__ void setup0(int* __restrict__ deg,
                       float* __restrict__ gsum,
                       const float* __restrict__ w2, const float* __restrict__ w3,
                       unsigned short* __restrict__ wt2, unsigned short* __restrict__ wt3,
                       const float* __restrict__ we1, const float* __restrict__ ae1,
                       const float* __restrict__ we2, const float* __restrict__ ae2,
                       const float* __restrict__ we3, const float* __restrict__ ae3,
                       float* __restrict__ kc,
                       const float* __restrict__ as2, const float* __restrict__ ad2,
                       const float* __restrict__ as3, const float* __restrict__ ad3,
                       const float* __restrict__ w1,
                       const float* __restrict__ as1, const float* __restrict__ ad1,
                       float* __restrict__ wastab, float* __restrict__ wadtab,
                       const int* __restrict__ batch, int* __restrict__ gstart, int n) {
    int i = blockIdx.x * 256 + threadIdx.x;
    if (i < n) deg[i] = 0;
    if (i < NGRAPH * HCDIM) gsum[i] = 0.f;
    if (i < WEXT * HCDIM) {
        int nn = i >> 7, k = i & 127;
        float v2, v3;
        if (nn < HCDIM) {
            v2 = w2[k * HCDIM + nn];
            v3 = w3[k * HCDIM + nn];
        } else if (nn < HCDIM + NHEAD) {
            int h = nn - HCDIM;
            float s2 = 0.f, s3 = 0.f;
#pragma unroll
            for (int c = 0; c < CDIM; ++c) {
                s2 += w2[k * HCDIM + h * CDIM + c] * as2[h * CDIM + c];
                s3 += w3[k * HCDIM + h * CDIM + c] * as3[h * CDIM + c];
            }
            v2 = s2; v3 = s3;
        } else {
            int h = nn - HCDIM - NHEAD;
            float s2 = 0.f, s3 = 0.f;
#pragma unroll
            for (int c = 0; c < CDIM; ++c) {
                s2 += w2[k * HCDIM + h * CDIM + c] * ad2[h * CDIM + c];
                s3 += w3[k * HCDIM + h * CDIM + c] * ad3[h * CDIM + c];
            }
            v2 = s2; v3 = s3;
        }
        wt2[nn * HCDIM + k] = f2bf(v2);
        wt3[nn * HCDIM + k] = f2bf(v3);
    }
    if (i < 24) {
        int l = i >> 3, h = i & 7;
        const float* we = (l == 0) ? we1 : ((l == 1) ? we2 : we3);
        const float* ae = (l == 0) ? ae1 : ((l == 1) ? ae2 : ae3);
        float s = 0.f;
        for (int c = 0; c < CDIM; ++c) s += we[h * CDIM + c] * ae[h * CDIM + c];
        kc[i] = s;
    }
    if (i >= 18560 && i <= 18560 + NGRAPH) {   // graph bounds, disjoint range
        int g = i - 18560;
        int lo = 0, hi = n;
        while (lo < hi) {
            int mid = (lo + hi) >> 1;
            if (batch[mid] < g) lo = mid + 1; else hi = mid;
        }
        gstart[g] = lo;
    }
    if (i >= 18700 && i < 18732) {   // layer-1 coeff tables [4][8]
        int t = i - 18700;
        int k = t >> 3, h = t & 7;
        float ss = 0.f, sd = 0.f;
#pragma unroll
        for (int c = 0; c < CDIM; ++c) {
            ss += w1[k * HCDIM + h * CDIM + c] * as1[h * CDIM + c];
            sd += w1[k * HCDIM + h * CDIM + c] * ad1[h * CDIM + c];
        }
        wastab[t] = ss;
        wadtab[t] = sd;
    }
}

// counts degree AND records each edge's within-dst rank so scatter is atomic-free.
__global__ void count_deg(const int* __restrict__ dst, int* __restrict__ deg,
                          int* __restrict__ erank, int E) {
    int e = blockIdx.x * 256 + threadIdx.x;
    if (e >= E) return;
    erank[e] = atomicAdd(&deg[dst[e]], 1);
}

// per-1024-node-tile bitonic sort by degree -> perm.  Groups equal-degree
// nodes so each aggregate wave's 4 nodes have ~identical edge-loop trip
// counts (kills intra-wave divergence).  Bit-identical results: only the
// node->lane-group assignment changes.
__global__ __launch_bounds__(512) void sort_tile(const int* __restrict__ deg,
                                                 int* __restrict__ perm, int n) {
    __shared__ unsigned key[1024];
    const int base = blockIdx.x << 10;
    const int t = threadIdx.x;
    for (int j = t; j < 1024; j += 512) {
        int i = base + j;
        unsigned d = (i < n) ? (unsigned)deg[i] : 0x1FFFFFu;   // pads sort to end
        key[j] = (d << 11) | (unsigned)j;
    }
    __syncthreads();
    for (int k = 2; k <= 1024; k <<= 1) {
        for (int jj = k >> 1; jj > 0; jj >>= 1) {
            for (int idx = t; idx < 1024; idx += 512) {
                int ixj = idx ^ jj;
                if (ixj > idx) {
                    unsigned a = key[idx], b = key[ixj];
                    bool asc = ((idx & k) == 0);
                    bool sw = asc ? (a > b) : (a < b);
                    if (sw) { key[idx] = b; key[ixj] = a; }
                }
            }
            __syncthreads();
        }
    }
    for (int j = t; j < 1024; j += 512) {
        int i = base + j;
        if (i < n) perm[i] = base + (int)(key[j] & 2047u);
    }
}

__global__ __launch_bounds__(512) void block_sum(const int* __restrict__ deg,
                                                 int* __restrict__ bsum, int n) {
    __shared__ int s[512];
    int i = blockIdx.x * 512 + threadIdx.x;
    s[threadIdx.x] = (i < n) ? deg[i] : 0;
    __syncthreads();
    for (int off = 256; off > 0; off >>= 1) {
        if (threadIdx.x < off) s[threadIdx.x] += s[threadIdx.x + off];
        __syncthreads();
    }
    if (threadIdx.x == 0) bsum[blockIdx.x] = s[0];
}

// fused: every block scans the (<=512-entry) bsum array in LDS AND its own
// 512-entry deg slice, producing eoff directly.
__global__ __launch_bounds__(512) void scan_final2(const int* __restrict__ deg,
                                                   const int* __restrict__ bsum, int nb,
                                                   int* __restrict__ eoff, int n) {
    __shared__ int ls[512];
    __shared__ int s[512];
    const int t = threadIdx.x;
    ls[t] = (t < nb) ? bsum[t] : 0;
    int i = blockIdx.x * 512 + t;
    s[t] = (i < n) ? deg[i] : 0;
    __syncthreads();
    for (int off = 1; off < 512; off <<= 1) {
        int a1 = (t >= off) ? ls[t - off] : 0;
        int a2 = (t >= off) ? s[t - off] : 0;
        __syncthreads();
        ls[t] += a1; s[t] += a2;
        __syncthreads();
    }
    int base = (blockIdx.x > 0) ? ls[blockIdx.x - 1] : 0;   // exclusive block base
    if (i < n) eoff[i + 1] = base + s[t];
    if (i == 0) eoff[0] = 0;
}

// atomic-free scatter: position = eoff[dst] + precomputed rank.
__global__ void scatter_edges(const int* __restrict__ src, const int* __restrict__ dst,
                              const float* __restrict__ eattr,
                              const int* __restrict__ eoff,
                              const int* __restrict__ erank,
                              int2* __restrict__ epack, int E) {
    int e = blockIdx.x * 256 + threadIdx.x;
    if (e >= E) return;
    int p = eoff[dst[e]] + erank[e];
    epack[p] = make_int2(src[e], __float_as_int(eattr[e]));
}

// ---------------------------------------------------------------- layer-1 aggregate

// h is rank-4:  Σ_e w_e·(x_e@W1) = (Σ_e w_e·x_e)@W1.
// FOUR nodes per wave (16 lanes x 8 channels each); prefetched epack.
// Node ids come from the degree-sorted perm (divergence-free waves).
__global__ __launch_bounds__(256) void gat_aggregate1(
    const float* __restrict__ x,        // [n,4]
    const int2*  __restrict__ epack,    // [E] dst-sorted {src, bits(eattr)}
    const int*   __restrict__ eoff,     // [n+1]
    const int*   __restrict__ perm,     // [n] degree-sorted node ids
    const float* __restrict__ w1,       // [4][128]
    const float* __restrict__ wastab,   // [4][8]
    const float* __restrict__ wadtab,   // [4][8]
    const float* __restrict__ kc,       // [8]
    const float* __restrict__ bias,     // [128]
    unsigned short* __restrict__ outbf, // [n,128] bf16
    int n) {
    const int lane = threadIdx.x & 63;
    const int l16 = lane & 15;
    int lin = ((blockIdx.x * 256 + threadIdx.x) >> 6) * 4 + (lane >> 4);
    if (lin >= n) return;
    const int nid = perm[lin];
    const int h = l16 >> 1;           // 2 lanes per head
    const int c0 = l16 * 8;           // 8 contiguous channels per lane

    float was0 = wastab[0 * NHEAD + h], was1_ = wastab[1 * NHEAD + h];
    float was2 = wastab[2 * NHEAD + h], was3 = wastab[3 * NHEAD + h];
    float wad0 = wadtab[0 * NHEAD + h], wad1_ = wadtab[1 * NHEAD + h];
    float wad2 = wadtab[2 * NHEAD + h], wad3 = wadtab[3 * NHEAD + h];

    f32x4 xd = *(const f32x4*)(x + (((unsigned)nid) << 2));
    const float adst_h = xd[0] * wad0 + xd[1] * wad1_ + xd[2] * wad2 + xd[3] * wad3;
    const float k_h = kc[h];
    const int e0 = eoff[nid], e1 = eoff[nid + 1];

    float den = 0.f;
    f32x4 acc4 = (f32x4){0.f, 0.f, 0.f, 0.f};   // Σ w_e · x_e

    if (e0 < e1) {
        int2 ep[4];
#pragma unroll
        for (int j = 0; j < 4; ++j) {
            int idx = e0 + j; idx = (idx < e1) ? idx : (e1 - 1);
            ep[j] = epack[idx];
        }
        for (int base = e0; base < e1; base += 4) {
            int2 epn[4];
#pragma unroll
            for (int j = 0; j < 4; ++j) {        // prefetch next group (clamped)
                int idx = base + 4 + j; idx = (idx < e1) ? idx : (e1 - 1);
                epn[j] = epack[idx];
            }
            f32x4 xs[4];
#pragma unroll
            for (int j = 0; j < 4; ++j)
                xs[j] = *(const f32x4*)(x + (((unsigned)ep[j].x) << 2));
#pragma unroll
            for (int j = 0; j < 4; ++j) {
                bool valid = (base + j < e1);
                float as_e = xs[j][0] * was0 + xs[j][1] * was1_ +
                             xs[j][2] * was2 + xs[j][3] * was3;
                float a = as_e + adst_h + __int_as_float(ep[j].y) * k_h;
                a = (a > 0.f) ? a : 0.2f * a;
                float w = valid ? __expf(a) : 0.f;
                den += w;
                acc4 += xs[j] * w;               // 2x v_pk_fma_f32
            }
#pragma unroll
            for (int j = 0; j < 4; ++j) ep[j] = epn[j];
        }
    }

    // epilogue: expand acc4 through 8 W1 columns (once per node)
    float inv = 1.f / (den + 1e-16f);
    short8 o;
#pragma unroll
    for (int c = 0; c < 8; ++c) {
        float oc = acc4[0] * w1[0 * HCDIM + c0 + c] + acc4[1] * w1[1 * HCDIM + c0 + c] +
                   acc4[2] * w1[2 * HCDIM + c0 + c] + acc4[3] * w1[3 * HCDIM + c0 + c];
        oc = fmaxf(oc * inv + bias[c0 + c], 0.f);
        o[c] = (short)f2bf(oc);
    }
    *(short8*)(outbf + (long)nid * HCDIM + c0) = o;
}

// ---------------------------------------------------------------- gemm

// layers 2/3: [n,128] @ [128,144], plain bf16 MFMA, W staged in padded LDS.
// cols 0..127 -> Ybf (bf16, 256B-aligned rows); dst-coeff cols -> adst fp32.
// src coeffs are NOT materialized: the aggregate recomputes them in-register.
__global__ __launch_bounds__(256) void gemm_mfma(const unsigned short* __restrict__ A,
                                                 const unsigned short* __restrict__ Wt,
                                                 unsigned short* __restrict__ Ybf,
                                                 float* __restrict__ adstn, int n) {
    __shared__ unsigned short sW[WEXT][SWPAD];
    for (int i = threadIdx.x; i < WEXT * 16; i += 256) {
        int r = i >> 4, c = (i & 15) << 3;
        *(short8*)&sW[r][c] = *(const short8*)(Wt + r * HCDIM + c);
    }
    __syncthreads();

    const int wave = threadIdx.x >> 6;
    const int lane = threadIdx.x & 63;
    const int quad = lane >> 4;
    const int l16  = lane & 15;
    const int rowbase = (blockIdx.x * 8 + wave * 2) * 16;

    f32x4 acc[2][9];
#pragma unroll
    for (int r = 0; r < 2; ++r)
#pragma unroll
        for (int t = 0; t < 9; ++t) acc[r][t] = (f32x4){0.f, 0.f, 0.f, 0.f};

#pragma unroll
    for (int kb = 0; kb < HCDIM; kb += 32) {
        short8 a[2];
#pragma unroll
        for (int r = 0; r < 2; ++r) {
            int row = rowbase + r * 16 + l16;
            row = (row < n) ? row : (n - 1);
            a[r] = *(const short8*)(A + (long)row * HCDIM + kb + quad * 8);
        }
#pragma unroll
        for (int nt = 0; nt < 9; ++nt) {
            short8 b = *(const short8*)(&sW[nt * 16 + l16][kb + quad * 8]);
#pragma unroll
            for (int r = 0; r < 2; ++r)
                acc[r][nt] = __builtin_amdgcn_mfma_f32_16x16x32_bf16(a[r], b, acc[r][nt], 0, 0, 0);
        }
    }

    // C/D layout: col = l16, row_local = quad*4 + reg
#pragma unroll
    for (int r = 0; r < 2; ++r) {
#pragma unroll
        for (int reg = 0; reg < 4; ++reg) {
            int row = rowbase + r * 16 + quad * 4 + reg;
            if (row < n) {
                unsigned short* yp = Ybf + (long)row * HCDIM + l16;
#pragma unroll
                for (int nt = 0; nt < 8; ++nt) yp[nt * 16] = f2bf(acc[r][nt][reg]);
                if (l16 >= 8) adstn[row * NHEAD + (l16 - 8)] = acc[r][8][reg];
            }
        }
    }
}

// ---------------------------------------------------------------- aggregate (layers 2/3)

// FOUR nodes per wave (16 lanes x 8 bf16 channels each); single pass, no
// max-subtraction. Edge loop software-pipelined (epack prefetch). The src
// attention coefficient is computed IN-REGISTER from the gathered row:
// as_e = partial_dot(8ch) + shfl_xor(partial, 1). Node ids from the
// degree-sorted perm (divergence-free waves).
__global__ __launch_bounds__(256) void gat_aggregate(
    const unsigned short* __restrict__ hlin, // [n,128] bf16
    const float* __restrict__ adst,     // [n,8]
    const float* __restrict__ asw,      // [8][16] this layer's att_src (fp32)
    const int2*  __restrict__ epack,    // [E] dst-sorted {src, bits(eattr)}
    const int*   __restrict__ eoff,     // [n+1]
    const int*   __restrict__ perm,     // [n] degree-sorted node ids
    const float* __restrict__ kc,       // [8] this layer
    const float* __restrict__ bias,     // [128]
    unsigned short* __restrict__ out,   // [n,128] bf16
    int n, int use_loop) {
    const int lane = threadIdx.x & 63;
    const int l16 = lane & 15;
    int lin = ((blockIdx.x * 256 + threadIdx.x) >> 6) * 4 + (lane >> 4);
    if (lin >= n) return;
    const int nid = perm[lin];
    const int h = l16 >> 1;           // 2 lanes per head
    const int c0 = l16 * 8;           // 8 contiguous channels per lane

    // this lane's 8 att_src coeffs (channel-within-head = (l16&1)*8 + k)
    const float* asrow = asw + h * CDIM + (l16 & 1) * 8;
    const f32x2 wp0 = *(const f32x2*)(asrow + 0);
    const f32x2 wp1 = *(const f32x2*)(asrow + 2);
    const f32x2 wp2 = *(const f32x2*)(asrow + 4);
    const f32x2 wp3 = *(const f32x2*)(asrow + 6);

    const float adst_h = adst[nid * NHEAD + h];
    const float k_h = kc[h];
    const int e0 = eoff[nid], e1 = eoff[nid + 1];

    float den = 0.f, sume = 0.f;
    f32x2 acc[4];
#pragma unroll
    for (int p = 0; p < 4; ++p) acc[p] = (f32x2){0.f, 0.f};

    if (e0 < e1) {
        int2 ep[4];
#pragma unroll
        for (int j = 0; j < 4; ++j) {
            int idx = e0 + j; idx = (idx < e1) ? idx : (e1 - 1);
            ep[j] = epack[idx];
        }
        for (int base = e0; base < e1; base += 4) {
            int2 epn[4];
#pragma unroll
            for (int j = 0; j < 4; ++j) {        // prefetch next group (clamped)
                int idx = base + 4 + j; idx = (idx < e1) ? idx : (e1 - 1);
                epn[j] = epack[idx];
            }
            uint4 hv[4];
#pragma unroll
            for (int j = 0; j < 4; ++j)
                hv[j] = *(const uint4*)(hlin + (((unsigned)ep[j].x) << 7) + c0);
#pragma unroll
            for (int j = 0; j < 4; ++j) {
                bool valid = (base + j < e1);
                f32x2 p0 = bfpair(hv[j].x), p1 = bfpair(hv[j].y);
                f32x2 p2 = bfpair(hv[j].z), p3 = bfpair(hv[j].w);
                // src-coeff partial dot over this lane's 8 channels
                f32x2 ds = p0 * wp0 + p1 * wp1 + p2 * wp2 + p3 * wp3;
                float part = ds[0] + ds[1];
                float as_e = part + __shfl_xor(part, 1, 64);
                float ea = __int_as_float(ep[j].y);
                float a = as_e + adst_h + ea * k_h;
                a = (a > 0.f) ? a : 0.2f * a;
                float w = valid ? __expf(a) : 0.f;
                sume += valid ? ea : 0.f;
                den += w;
                acc[0] += p0 * w;   // v_pk_fma_f32
                acc[1] += p1 * w;
                acc[2] += p2 * w;
                acc[3] += p3 * w;
            }
#pragma unroll
            for (int j = 0; j < 4; ++j) ep[j] = epn[j];
        }
    }

    if (use_loop) {   // self-loop; attr = mean of incoming eattr
        float fl = sume / fmaxf((float)(e1 - e0), 1.f);
        uint4 hv = *(const uint4*)(hlin + (((unsigned)nid) << 7) + c0);
        f32x2 p0 = bfpair(hv.x), p1 = bfpair(hv.y);
        f32x2 p2 = bfpair(hv.z), p3 = bfpair(hv.w);
        f32x2 ds = p0 * wp0 + p1 * wp1 + p2 * wp2 + p3 * wp3;
        float part = ds[0] + ds[1];
        float as_self = part + __shfl_xor(part, 1, 64);
        float a = as_self + adst_h + fl * k_h;
        a = (a > 0.f) ? a : 0.2f * a;
        float w = __expf(a);
        den += w;
        acc[0] += p0 * w;
        acc[1] += p1 * w;
        acc[2] += p2 * w;
        acc[3] += p3 * w;
    }

    float inv = 1.f / (den + 1e-16f);
    short8 o;
#pragma unroll
    for (int c = 0; c < 8; ++c) {
        float oc = fmaxf(acc[c >> 1][c & 1] * inv + bias[c0 + c], 0.f);
        o[c] = (short)f2bf(oc);
    }
    *(short8*)(out + (long)nid * HCDIM + c0) = o;
}

// ---------------------------------------------------------------- pool + MLP

// segmented pool over bf16 h3: block = (graph g, chunk) over the CONTIGUOUS
// row range gstart[g]..gstart[g+1]. One atomic per column per chunk.
__global__ __launch_bounds__(128) void pool_seg(const unsigned short* __restrict__ H,
                                                const int* __restrict__ gstart,
                                                float* __restrict__ gsum) {
    const int c = threadIdx.x;            // 0..127
    const int g = blockIdx.x >> 3;
    const int chunk = blockIdx.x & 7;
    int s0 = gstart[g], s1 = gstart[g + 1];
    int len = s1 - s0;
    if (len <= 0) return;
    int cl = (len + 7) >> 3;
    int i0 = s0 + chunk * cl;
    int i1 = min(i0 + cl, s1);
    if (i0 >= i1) return;
    float acc = 0.f;
    int i = i0;
    for (; i + 4 <= i1; i += 4) {
        float v0 = bf2f(H[(long)i * HCDIM + c]);
        float v1 = bf2f(H[(long)(i + 1) * HCDIM + c]);
        float v2 = bf2f(H[(long)(i + 2) * HCDIM + c]);
        float v3 = bf2f(H[(long)(i + 3) * HCDIM + c]);
        acc += (v0 + v1) + (v2 + v3);
    }
    for (; i < i1; ++i) acc += bf2f(H[(long)i * HCDIM + c]);
    atomicAdd(&gsum[g * HCDIM + c], acc);
}

__global__ __launch_bounds__(64) void mlp_kernel(const float* __restrict__ gsum,
                                                 const int* __restrict__ gstart,
                                                 const float* __restrict__ fw1,
                                                 const float* __restrict__ fb1,
                                                 const float* __restrict__ fw2,
                                                 const float* __restrict__ fb2,
                                                 float* __restrict__ out) {
    const int g = blockIdx.x;
    const int j = threadIdx.x;            // 0..63
    __shared__ float emb[HCDIM];
    __shared__ float gh[64];
    int cnt = gstart[g + 1] - gstart[g];
    float invc = 1.f / fmaxf((float)cnt, 1.f);
    emb[j] = gsum[g * HCDIM + j] * invc;
    emb[j + 64] = gsum[g * HCDIM + 64 + j] * invc;
    __syncthreads();
    float a = fb1[j];
    for (int k = 0; k < HCDIM; ++k) a += emb[k] * fw1[k * 64 + j];
    gh[j] = fmaxf(a, 0.f);
    __syncthreads();
    if (j < 2) {
        float o = fb2[j];
        for (int k = 0; k < 64; ++k) o += gh[k] * fw2[k * 2 + j];
        out[g * 2 + j] = o;
    }
}

// ---------------------------------------------------------------- launcher

extern "C" void kernel_launch(void* const* d_in, const int* in_sizes, int n_in,
                              void* d_out, int out_size, void* d_ws, size_t ws_size,
                              hipStream_t stream) {
    const float* x     = (const float*)d_in[0];
    const int*   eidx  = (const int*)d_in[1];
    const float* eattr = (const float*)d_in[2];
    const int*   batch = (const int*)d_in[3];
    const float* w1  = (const float*)d_in[4];
    const float* as1 = (const float*)d_in[5];
    const float* ad1 = (const float*)d_in[6];
    const float* we1 = (const float*)d_in[7];
    const float* ae1 = (const float*)d_in[8];
    const float* b1  = (const float*)d_in[9];
    const float* w2  = (const float*)d_in[10];
    const float* as2 = (const float*)d_in[11];
    const float* ad2 = (const float*)d_in[12];
    const float* we2 = (const float*)d_in[13];
    const float* ae2 = (const float*)d_in[14];
    const float* b2  = (const float*)d_in[15];
    const float* w3  = (const float*)d_in[16];
    const float* as3 = (const float*)d_in[17];
    const float* ad3 = (const float*)d_in[18];
    const float* we3 = (const float*)d_in[19];
    const float* ae3 = (const float*)d_in[20];
    const float* b3  = (const float*)d_in[21];
    const float* fw1 = (const float*)d_in[22];
    const float* fb1 = (const float*)d_in[23];
    const float* fw2 = (const float*)d_in[24];
    const float* fb2 = (const float*)d_in[25];

    const int N = in_sizes[3];
    const int E = in_sizes[2];
    const int* src = eidx;
    const int* dst = eidx + E;

    // workspace carve
    char* p = (char*)d_ws;
    auto alloc = [&](size_t bytes) {
        void* r = (void*)p;
        p += (bytes + 255) & ~(size_t)255;
        return r;
    };
    unsigned short* Abf = (unsigned short*)alloc((size_t)N * HCDIM * 2);  // gemm out
    unsigned short* Bbf = (unsigned short*)alloc((size_t)N * HCDIM * 2);  // agg out
    float* adstA  = (float*)alloc((size_t)N * NHEAD * 4);
    float* adstB  = (float*)alloc((size_t)N * NHEAD * 4);
    int*   deg    = (int*)alloc((size_t)N * 4);
    int*   eoff   = (int*)alloc((size_t)(N + 1) * 4);
    int*   erank  = (int*)alloc((size_t)E * 4);
    int2*  epack  = (int2*)alloc((size_t)E * 8);
    int*   bsum   = (int*)alloc(((size_t)(N + 511) / 512) * 4);
    int*   perm   = (int*)alloc((size_t)N * 4);
    float* kc     = (float*)alloc(24 * 4);
    int*   gstart = (int*)alloc((NGRAPH + 1) * 4);
    float* gsum   = (float*)alloc(NGRAPH * HCDIM * 4);
    float* wastab = (float*)alloc(32 * 4);
    float* wadtab = (float*)alloc(32 * 4);
    unsigned short* wt2 = (unsigned short*)alloc(WEXT * HCDIM * 2);
    unsigned short* wt3 = (unsigned short*)alloc(WEXT * HCDIM * 2);

    const int NB = (N + 255) / 256;
    const int NB512 = (N + 511) / 512;
    const int EB = (E + 255) / 256;
    const int NTILE = (N + 1023) / 1024;
    const int AGG_BLOCKS = (((N + 3) / 4) * 64 + 255) / 256;   // 4 nodes/wave
    const int GEMM_BLOCKS = (N + 127) / 128;                   // 128 rows per block

    setup0<<<NB, 256, 0, stream>>>(deg, gsum,
                                   w2, w3, wt2, wt3,
                                   we1, ae1, we2, ae2, we3, ae3, kc,
                                   as2, ad2, as3, ad3,
                                   w1, as1, ad1, wastab, wadtab,
                                   batch, gstart, N);
    count_deg<<<EB, 256, 0, stream>>>(dst, deg, erank, E);
    sort_tile<<<NTILE, 512, 0, stream>>>(deg, perm, N);
    block_sum<<<NB512, 512, 0, stream>>>(deg, bsum, N);
    scan_final2<<<NB512, 512, 0, stream>>>(deg, bsum, NB512, eoff, N);
    scatter_edges<<<EB, 256, 0, stream>>>(src, dst, eattr, eoff, erank, epack, E);

    // layer 1 (no self loops): rank-4 accumulate + epilogue W1 expand -> bf16
    gat_aggregate1<<<AGG_BLOCKS, 256, 0, stream>>>(x, epack, eoff, perm, w1, wastab,
                                                   wadtab, kc + 0, b1, Bbf, N);
    // layer 2: gemm (bf16, LDS-staged W) emits bf16 h2 + adst2 (asrc in-register)
    gemm_mfma<<<GEMM_BLOCKS, 256, 0, stream>>>(Bbf, wt2, Abf, adstB, N);
    gat_aggregate<<<AGG_BLOCKS, 256, 0, stream>>>(Abf, adstB, as2, epack, eoff, perm,
                                                  kc + 8, b2, Bbf, N, 1);
    // layer 3
    gemm_mfma<<<GEMM_BLOCKS, 256, 0, stream>>>(Bbf, wt3, Abf, adstA, N);
    gat_aggregate<<<AGG_BLOCKS, 256, 0, stream>>>(Abf, adstA, as3, epack, eoff, perm,
                                                  kc + 16, b3, Bbf, N, 1);

    // segmented mean-pool (bf16 in) + MLP head
    pool_seg<<<NGRAPH * 8, 128, 0, stream>>>(Bbf, gstart, gsum);
    mlp_kernel<<<NGRAPH, 64, 0, stream>>>(gsum, gstart, fw1, fb1, fw2, fb2, (float*)d_out);
}

// Round 8
// 305.612 us; speedup vs baseline: 1.1369x; 1.1369x over previous
//
#include <hip/hip_runtime.h>
#include <hip/hip_bf16.h>
#include <math.h>

#define NHEAD 8
#define CDIM 16
#define HCDIM 128
#define NGRAPH 64
#define WEXT 144   // 128 gemm cols + 8 src-coeff cols + 8 dst-coeff cols
#define SWPAD 136  // +8 shorts pad: row stride 68 dwords == 4 mod 32 banks

typedef __attribute__((ext_vector_type(8))) short short8;
typedef __attribute__((ext_vector_type(4))) float f32x4;
typedef __attribute__((ext_vector_type(2))) float f32x2;

static __device__ __forceinline__ unsigned short f2bf(float f) {
    unsigned u = __float_as_uint(f);
    unsigned r = (u + 0x7FFF + ((u >> 16) & 1)) >> 16;   // rne
    return (unsigned short)r;
}
static __device__ __forceinline__ float bf2f(unsigned short s) {
    return __uint_as_float(((unsigned)s) << 16);
}
// encode one float -> fp8 e4m3 byte via HW cvt (RNE)
static __device__ __forceinline__ unsigned char f2fp8(float v) {
    int r = __builtin_amdgcn_cvt_pk_fp8_f32(v, v, 0, false);
    return (unsigned char)(r & 0xff);
}

// ---------------------------------------------------------------- setup

// merged: zero deg/gsum + kcoef + graph_bounds + extended weight build (bf16)
// + layer-1 coeff tables was1/wad1 [4][8]
__global__ void setup0(int* __restrict__ deg,
                       float* __restrict__ gsum,
                       const float* __restrict__ w2, const float* __restrict__ w3,
                       unsigned short* __restrict__ wt2, unsigned short* __restrict__ wt3,
                       const float* __restrict__ we1, const float* __restrict__ ae1,
                       const float* __restrict__ we2, const float* __restrict__ ae2,
                       const float* __restrict__ we3, const float* __restrict__ ae3,
                       float* __restrict__ kc,
                       const float* __restrict__ as2, const float* __restrict__ ad2,
                       const float* __restrict__ as3, const float* __restrict__ ad3,
                       const float* __restrict__ w1,
                       const float* __restrict__ as1, const float* __restrict__ ad1,
                       float* __restrict__ wastab, float* __restrict__ wadtab,
                       const int* __restrict__ batch, int* __restrict__ gstart, int n) {
    int i = blockIdx.x * 256 + threadIdx.x;
    if (i < n) deg[i] = 0;
    if (i < NGRAPH * HCDIM) gsum[i] = 0.f;
    if (i < WEXT * HCDIM) {
        int nn = i >> 7, k = i & 127;
        float v2, v3;
        if (nn < HCDIM) {
            v2 = w2[k * HCDIM + nn];
            v3 = w3[k * HCDIM + nn];
        } else if (nn < HCDIM + NHEAD) {
            int h = nn - HCDIM;
            float s2 = 0.f, s3 = 0.f;
#pragma unroll
            for (int c = 0; c < CDIM; ++c) {
                s2 += w2[k * HCDIM + h * CDIM + c] * as2[h * CDIM + c];
                s3 += w3[k * HCDIM + h * CDIM + c] * as3[h * CDIM + c];
            }
            v2 = s2; v3 = s3;
        } else {
            int h = nn - HCDIM - NHEAD;
            float s2 = 0.f, s3 = 0.f;
#pragma unroll
            for (int c = 0; c < CDIM; ++c) {
                s2 += w2[k * HCDIM + h * CDIM + c] * ad2[h * CDIM + c];
                s3 += w3[k * HCDIM + h * CDIM + c] * ad3[h * CDIM + c];
            }
            v2 = s2; v3 = s3;
        }
        wt2[nn * HCDIM + k] = f2bf(v2);
        wt3[nn * HCDIM + k] = f2bf(v3);
    }
    if (i < 24) {
        int l = i >> 3, h = i & 7;
        const float* we = (l == 0) ? we1 : ((l == 1) ? we2 : we3);
        const float* ae = (l == 0) ? ae1 : ((l == 1) ? ae2 : ae3);
        float s = 0.f;
        for (int c = 0; c < CDIM; ++c) s += we[h * CDIM + c] * ae[h * CDIM + c];
        kc[i] = s;
    }
    if (i >= 18560 && i <= 18560 + NGRAPH) {   // graph bounds, disjoint range
        int g = i - 18560;
        int lo = 0, hi = n;
        while (lo < hi) {
            int mid = (lo + hi) >> 1;
            if (batch[mid] < g) lo = mid + 1; else hi = mid;
        }
        gstart[g] = lo;
    }
    if (i >= 18700 && i < 18732) {   // layer-1 coeff tables [4][8]
        int t = i - 18700;
        int k = t >> 3, h = t & 7;
        float ss = 0.f, sd = 0.f;
#pragma unroll
        for (int c = 0; c < CDIM; ++c) {
            ss += w1[k * HCDIM + h * CDIM + c] * as1[h * CDIM + c];
            sd += w1[k * HCDIM + h * CDIM + c] * ad1[h * CDIM + c];
        }
        wastab[t] = ss;
        wadtab[t] = sd;
    }
}

// counts degree AND records each edge's within-dst rank so scatter is atomic-free.
__global__ void count_deg(const int* __restrict__ dst, int* __restrict__ deg,
                          int* __restrict__ erank, int E) {
    int e = blockIdx.x * 256 + threadIdx.x;
    if (e >= E) return;
    erank[e] = atomicAdd(&deg[dst[e]], 1);
}

__global__ __launch_bounds__(512) void block_sum(const int* __restrict__ deg,
                                                 int* __restrict__ bsum, int n) {
    __shared__ int s[512];
    int i = blockIdx.x * 512 + threadIdx.x;
    s[threadIdx.x] = (i < n) ? deg[i] : 0;
    __syncthreads();
    for (int off = 256; off > 0; off >>= 1) {
        if (threadIdx.x < off) s[threadIdx.x] += s[threadIdx.x + off];
        __syncthreads();
    }
    if (threadIdx.x == 0) bsum[blockIdx.x] = s[0];
}

// fused: every block scans the (<=512-entry) bsum array in LDS AND its own
// 512-entry deg slice, producing eoff directly.
__global__ __launch_bounds__(512) void scan_final2(const int* __restrict__ deg,
                                                   const int* __restrict__ bsum, int nb,
                                                   int* __restrict__ eoff, int n) {
    __shared__ int ls[512];
    __shared__ int s[512];
    const int t = threadIdx.x;
    ls[t] = (t < nb) ? bsum[t] : 0;
    int i = blockIdx.x * 512 + t;
    s[t] = (i < n) ? deg[i] : 0;
    __syncthreads();
    for (int off = 1; off < 512; off <<= 1) {
        int a1 = (t >= off) ? ls[t - off] : 0;
        int a2 = (t >= off) ? s[t - off] : 0;
        __syncthreads();
        ls[t] += a1; s[t] += a2;
        __syncthreads();
    }
    int base = (blockIdx.x > 0) ? ls[blockIdx.x - 1] : 0;   // exclusive block base
    if (i < n) eoff[i + 1] = base + s[t];
    if (i == 0) eoff[0] = 0;
}

// atomic-free scatter: position = eoff[dst] + precomputed rank.
__global__ void scatter_edges(const int* __restrict__ src, const int* __restrict__ dst,
                              const float* __restrict__ eattr,
                              const int* __restrict__ eoff,
                              const int* __restrict__ erank,
                              int2* __restrict__ epack, int E) {
    int e = blockIdx.x * 256 + threadIdx.x;
    if (e >= E) return;
    int p = eoff[dst[e]] + erank[e];
    epack[p] = make_int2(src[e], __float_as_int(eattr[e]));
}

// ---------------------------------------------------------------- layer-1 aggregate

// h is rank-4:  Σ_e w_e·(x_e@W1) = (Σ_e w_e·x_e)@W1.
// FOUR nodes per wave (16 lanes x 8 channels each); prefetched epack.
__global__ __launch_bounds__(256) void gat_aggregate1(
    const float* __restrict__ x,        // [n,4]
    const int2*  __restrict__ epack,    // [E] dst-sorted {src, bits(eattr)}
    const int*   __restrict__ eoff,     // [n+1]
    const float* __restrict__ w1,       // [4][128]
    const float* __restrict__ wastab,   // [4][8]
    const float* __restrict__ wadtab,   // [4][8]
    const float* __restrict__ kc,       // [8]
    const float* __restrict__ bias,     // [128]
    unsigned short* __restrict__ outbf, // [n,128] bf16
    int n) {
    const int lane = threadIdx.x & 63;
    const int l16 = lane & 15;
    int nid = ((blockIdx.x * 256 + threadIdx.x) >> 6) * 4 + (lane >> 4);
    if (nid >= n) return;
    const int h = l16 >> 1;           // 2 lanes per head
    const int c0 = l16 * 8;           // 8 contiguous channels per lane

    float was0 = wastab[0 * NHEAD + h], was1_ = wastab[1 * NHEAD + h];
    float was2 = wastab[2 * NHEAD + h], was3 = wastab[3 * NHEAD + h];
    float wad0 = wadtab[0 * NHEAD + h], wad1_ = wadtab[1 * NHEAD + h];
    float wad2 = wadtab[2 * NHEAD + h], wad3 = wadtab[3 * NHEAD + h];

    f32x4 xd = *(const f32x4*)(x + (((unsigned)nid) << 2));
    const float adst_h = xd[0] * wad0 + xd[1] * wad1_ + xd[2] * wad2 + xd[3] * wad3;
    const float k_h = kc[h];
    const int e0 = eoff[nid], e1 = eoff[nid + 1];

    float den = 0.f;
    f32x4 acc4 = (f32x4){0.f, 0.f, 0.f, 0.f};   // Σ w_e · x_e

    if (e0 < e1) {
        int2 ep[4];
#pragma unroll
        for (int j = 0; j < 4; ++j) {
            int idx = e0 + j; idx = (idx < e1) ? idx : (e1 - 1);
            ep[j] = epack[idx];
        }
        for (int base = e0; base < e1; base += 4) {
            int2 epn[4];
#pragma unroll
            for (int j = 0; j < 4; ++j) {        // prefetch next group (clamped)
                int idx = base + 4 + j; idx = (idx < e1) ? idx : (e1 - 1);
                epn[j] = epack[idx];
            }
            f32x4 xs[4];
#pragma unroll
            for (int j = 0; j < 4; ++j)
                xs[j] = *(const f32x4*)(x + (((unsigned)ep[j].x) << 2));
#pragma unroll
            for (int j = 0; j < 4; ++j) {
                bool valid = (base + j < e1);
                float as_e = xs[j][0] * was0 + xs[j][1] * was1_ +
                             xs[j][2] * was2 + xs[j][3] * was3;
                float a = as_e + adst_h + __int_as_float(ep[j].y) * k_h;
                a = (a > 0.f) ? a : 0.2f * a;
                float w = valid ? __expf(a) : 0.f;
                den += w;
                acc4 += xs[j] * w;               // 2x v_pk_fma_f32
            }
#pragma unroll
            for (int j = 0; j < 4; ++j) ep[j] = epn[j];
        }
    }

    // epilogue: expand acc4 through 8 W1 columns (once per node)
    float inv = 1.f / (den + 1e-16f);
    short8 o;
#pragma unroll
    for (int c = 0; c < 8; ++c) {
        float oc = acc4[0] * w1[0 * HCDIM + c0 + c] + acc4[1] * w1[1 * HCDIM + c0 + c] +
                   acc4[2] * w1[2 * HCDIM + c0 + c] + acc4[3] * w1[3 * HCDIM + c0 + c];
        oc = fmaxf(oc * inv + bias[c0 + c], 0.f);
        o[c] = (short)f2bf(oc);
    }
    *(short8*)(outbf + (long)nid * HCDIM + c0) = o;
}

// ---------------------------------------------------------------- gemm

// layers 2/3: [n,128] @ [128,144], plain bf16 MFMA, W staged in padded LDS.
// cols 0..127 -> Y8 (FP8 e4m3, 128B rows — the gather payload, half the
// bytes of bf16); dst-coeff cols -> adst fp32.  src coeffs recomputed
// in-register by the aggregate from the fp8 row.
__global__ __launch_bounds__(256) void gemm_mfma(const unsigned short* __restrict__ A,
                                                 const unsigned short* __restrict__ Wt,
                                                 unsigned char* __restrict__ Y8,
                                                 float* __restrict__ adstn, int n) {
    __shared__ unsigned short sW[WEXT][SWPAD];
    for (int i = threadIdx.x; i < WEXT * 16; i += 256) {
        int r = i >> 4, c = (i & 15) << 3;
        *(short8*)&sW[r][c] = *(const short8*)(Wt + r * HCDIM + c);
    }
    __syncthreads();

    const int wave = threadIdx.x >> 6;
    const int lane = threadIdx.x & 63;
    const int quad = lane >> 4;
    const int l16  = lane & 15;
    const int rowbase = (blockIdx.x * 8 + wave * 2) * 16;

    f32x4 acc[2][9];
#pragma unroll
    for (int r = 0; r < 2; ++r)
#pragma unroll
        for (int t = 0; t < 9; ++t) acc[r][t] = (f32x4){0.f, 0.f, 0.f, 0.f};

#pragma unroll
    for (int kb = 0; kb < HCDIM; kb += 32) {
        short8 a[2];
#pragma unroll
        for (int r = 0; r < 2; ++r) {
            int row = rowbase + r * 16 + l16;
            row = (row < n) ? row : (n - 1);
            a[r] = *(const short8*)(A + (long)row * HCDIM + kb + quad * 8);
        }
#pragma unroll
        for (int nt = 0; nt < 9; ++nt) {
            short8 b = *(const short8*)(&sW[nt * 16 + l16][kb + quad * 8]);
#pragma unroll
            for (int r = 0; r < 2; ++r)
                acc[r][nt] = __builtin_amdgcn_mfma_f32_16x16x32_bf16(a[r], b, acc[r][nt], 0, 0, 0);
        }
    }

    // C/D layout: col = l16, row_local = quad*4 + reg
#pragma unroll
    for (int r = 0; r < 2; ++r) {
#pragma unroll
        for (int reg = 0; reg < 4; ++reg) {
            int row = rowbase + r * 16 + quad * 4 + reg;
            if (row < n) {
                unsigned char* yp = Y8 + (long)row * HCDIM + l16;
#pragma unroll
                for (int nt = 0; nt < 8; ++nt) yp[nt * 16] = f2fp8(acc[r][nt][reg]);
                if (l16 >= 8) adstn[row * NHEAD + (l16 - 8)] = acc[r][8][reg];
            }
        }
    }
}

// ---------------------------------------------------------------- aggregate (layers 2/3)

// FOUR nodes per wave (16 lanes x 8 fp8 channels each); single pass, no
// max-subtraction. Edge loop software-pipelined (epack prefetch). Gather is
// 8B/lane (fp8 row = 128B = 2 cachelines/edge). HW cvt unpacks fp8->f32.
// Src coeff computed in-register: as_e = partial_dot(8ch) + shfl_xor(.,1).
__global__ __launch_bounds__(256) void gat_aggregate(
    const unsigned char* __restrict__ h8, // [n,128] fp8 e4m3
    const float* __restrict__ adst,     // [n,8]
    const float* __restrict__ asw,      // [8][16] this layer's att_src (fp32)
    const int2*  __restrict__ epack,    // [E] dst-sorted {src, bits(eattr)}
    const int*   __restrict__ eoff,     // [n+1]
    const float* __restrict__ kc,       // [8] this layer
    const float* __restrict__ bias,     // [128]
    unsigned short* __restrict__ out,   // [n,128] bf16
    int n, int use_loop) {
    const int lane = threadIdx.x & 63;
    const int l16 = lane & 15;
    int nid = ((blockIdx.x * 256 + threadIdx.x) >> 6) * 4 + (lane >> 4);
    if (nid >= n) return;
    const int h = l16 >> 1;           // 2 lanes per head
    const int c0 = l16 * 8;           // 8 contiguous channels per lane (byte off = c0)

    // this lane's 8 att_src coeffs (channel-within-head = (l16&1)*8 + k)
    const float* asrow = asw + h * CDIM + (l16 & 1) * 8;
    const f32x2 wp0 = *(const f32x2*)(asrow + 0);
    const f32x2 wp1 = *(const f32x2*)(asrow + 2);
    const f32x2 wp2 = *(const f32x2*)(asrow + 4);
    const f32x2 wp3 = *(const f32x2*)(asrow + 6);

    const float adst_h = adst[nid * NHEAD + h];
    const float k_h = kc[h];
    const int e0 = eoff[nid], e1 = eoff[nid + 1];

    float den = 0.f, sume = 0.f;
    f32x2 acc[4];
#pragma unroll
    for (int p = 0; p < 4; ++p) acc[p] = (f32x2){0.f, 0.f};

    if (e0 < e1) {
        int2 ep[4];
#pragma unroll
        for (int j = 0; j < 4; ++j) {
            int idx = e0 + j; idx = (idx < e1) ? idx : (e1 - 1);
            ep[j] = epack[idx];
        }
        for (int base = e0; base < e1; base += 4) {
            int2 epn[4];
#pragma unroll
            for (int j = 0; j < 4; ++j) {        // prefetch next group (clamped)
                int idx = base + 4 + j; idx = (idx < e1) ? idx : (e1 - 1);
                epn[j] = epack[idx];
            }
            uint2 hv[4];
#pragma unroll
            for (int j = 0; j < 4; ++j)
                hv[j] = *(const uint2*)(h8 + (((unsigned)ep[j].x) << 7) + c0);
#pragma unroll
            for (int j = 0; j < 4; ++j) {
                bool valid = (base + j < e1);
                f32x2 p0 = __builtin_amdgcn_cvt_pk_f32_fp8((int)hv[j].x, false);
                f32x2 p1 = __builtin_amdgcn_cvt_pk_f32_fp8((int)hv[j].x, true);
                f32x2 p2 = __builtin_amdgcn_cvt_pk_f32_fp8((int)hv[j].y, false);
                f32x2 p3 = __builtin_amdgcn_cvt_pk_f32_fp8((int)hv[j].y, true);
                // src-coeff partial dot over this lane's 8 channels
                f32x2 ds = p0 * wp0 + p1 * wp1 + p2 * wp2 + p3 * wp3;
                float part = ds[0] + ds[1];
                float as_e = part + __shfl_xor(part, 1, 64);
                float ea = __int_as_float(ep[j].y);
                float a = as_e + adst_h + ea * k_h;
                a = (a > 0.f) ? a : 0.2f * a;
                float w = valid ? __expf(a) : 0.f;
                sume += valid ? ea : 0.f;
                den += w;
                acc[0] += p0 * w;   // v_pk_fma_f32
                acc[1] += p1 * w;
                acc[2] += p2 * w;
                acc[3] += p3 * w;
            }
#pragma unroll
            for (int j = 0; j < 4; ++j) ep[j] = epn[j];
        }
    }

    if (use_loop) {   // self-loop; attr = mean of incoming eattr
        float fl = sume / fmaxf((float)(e1 - e0), 1.f);
        uint2 hv = *(const uint2*)(h8 + (((unsigned)nid) << 7) + c0);
        f32x2 p0 = __builtin_amdgcn_cvt_pk_f32_fp8((int)hv.x, false);
        f32x2 p1 = __builtin_amdgcn_cvt_pk_f32_fp8((int)hv.x, true);
        f32x2 p2 = __builtin_amdgcn_cvt_pk_f32_fp8((int)hv.y, false);
        f32x2 p3 = __builtin_amdgcn_cvt_pk_f32_fp8((int)hv.y, true);
        f32x2 ds = p0 * wp0 + p1 * wp1 + p2 * wp2 + p3 * wp3;
        float part = ds[0] + ds[1];
        float as_self = part + __shfl_xor(part, 1, 64);
        float a = as_self + adst_h + fl * k_h;
        a = (a > 0.f) ? a : 0.2f * a;
        float w = __expf(a);
        den += w;
        acc[0] += p0 * w;
        acc[1] += p1 * w;
        acc[2] += p2 * w;
        acc[3] += p3 * w;
    }

    float inv = 1.f / (den + 1e-16f);
    short8 o;
#pragma unroll
    for (int c = 0; c < 8; ++c) {
        float oc = fmaxf(acc[c >> 1][c & 1] * inv + bias[c0 + c], 0.f);
        o[c] = (short)f2bf(oc);
    }
    *(short8*)(out + (long)nid * HCDIM + c0) = o;
}

// ---------------------------------------------------------------- pool + MLP

// segmented pool over bf16 h3: block = (graph g, chunk) over the CONTIGUOUS
// row range gstart[g]..gstart[g+1]. One atomic per column per chunk.
__global__ __launch_bounds__(128) void pool_seg(const unsigned short* __restrict__ H,
                                                const int* __restrict__ gstart,
                                                float* __restrict__ gsum) {
    const int c = threadIdx.x;            // 0..127
    const int g = blockIdx.x >> 3;
    const int chunk = blockIdx.x & 7;
    int s0 = gstart[g], s1 = gstart[g + 1];
    int len = s1 - s0;
    if (len <= 0) return;
    int cl = (len + 7) >> 3;
    int i0 = s0 + chunk * cl;
    int i1 = min(i0 + cl, s1);
    if (i0 >= i1) return;
    float acc = 0.f;
    int i = i0;
    for (; i + 4 <= i1; i += 4) {
        float v0 = bf2f(H[(long)i * HCDIM + c]);
        float v1 = bf2f(H[(long)(i + 1) * HCDIM + c]);
        float v2 = bf2f(H[(long)(i + 2) * HCDIM + c]);
        float v3 = bf2f(H[(long)(i + 3) * HCDIM + c]);
        acc += (v0 + v1) + (v2 + v3);
    }
    for (; i < i1; ++i) acc += bf2f(H[(long)i * HCDIM + c]);
    atomicAdd(&gsum[g * HCDIM + c], acc);
}

__global__ __launch_bounds__(64) void mlp_kernel(const float* __restrict__ gsum,
                                                 const int* __restrict__ gstart,
                                                 const float* __restrict__ fw1,
                                                 const float* __restrict__ fb1,
                                                 const float* __restrict__ fw2,
                                                 const float* __restrict__ fb2,
                                                 float* __restrict__ out) {
    const int g = blockIdx.x;
    const int j = threadIdx.x;            // 0..63
    __shared__ float emb[HCDIM];
    __shared__ float gh[64];
    int cnt = gstart[g + 1] - gstart[g];
    float invc = 1.f / fmaxf((float)cnt, 1.f);
    emb[j] = gsum[g * HCDIM + j] * invc;
    emb[j + 64] = gsum[g * HCDIM + 64 + j] * invc;
    __syncthreads();
    float a = fb1[j];
    for (int k = 0; k < HCDIM; ++k) a += emb[k] * fw1[k * 64 + j];
    gh[j] = fmaxf(a, 0.f);
    __syncthreads();
    if (j < 2) {
        float o = fb2[j];
        for (int k = 0; k < 64; ++k) o += gh[k] * fw2[k * 2 + j];
        out[g * 2 + j] = o;
    }
}

// ---------------------------------------------------------------- launcher

extern "C" void kernel_launch(void* const* d_in, const int* in_sizes, int n_in,
                              void* d_out, int out_size, void* d_ws, size_t ws_size,
                              hipStream_t stream) {
    const float* x     = (const float*)d_in[0];
    const int*   eidx  = (const int*)d_in[1];
    const float* eattr = (const float*)d_in[2];
    const int*   batch = (const int*)d_in[3];
    const float* w1  = (const float*)d_in[4];
    const float* as1 = (const float*)d_in[5];
    const float* ad1 = (const float*)d_in[6];
    const float* we1 = (const float*)d_in[7];
    const float* ae1 = (const float*)d_in[8];
    const float* b1  = (const float*)d_in[9];
    const float* w2  = (const float*)d_in[10];
    const float* as2 = (const float*)d_in[11];
    const float* ad2 = (const float*)d_in[12];
    const float* we2 = (const float*)d_in[13];
    const float* ae2 = (const float*)d_in[14];
    const float* b2  = (const float*)d_in[15];
    const float* w3  = (const float*)d_in[16];
    const float* as3 = (const float*)d_in[17];
    const float* ad3 = (const float*)d_in[18];
    const float* we3 = (const float*)d_in[19];
    const float* ae3 = (const float*)d_in[20];
    const float* b3  = (const float*)d_in[21];
    const float* fw1 = (const float*)d_in[22];
    const float* fb1 = (const float*)d_in[23];
    const float* fw2 = (const float*)d_in[24];
    const float* fb2 = (const float*)d_in[25];

    const int N = in_sizes[3];
    const int E = in_sizes[2];
    const int* src = eidx;
    const int* dst = eidx + E;

    // workspace carve
    char* p = (char*)d_ws;
    auto alloc = [&](size_t bytes) {
        void* r = (void*)p;
        p += (bytes + 255) & ~(size_t)255;
        return r;
    };
    unsigned char*  A8  = (unsigned char*)alloc((size_t)N * HCDIM);       // gemm out fp8
    unsigned short* Bbf = (unsigned short*)alloc((size_t)N * HCDIM * 2);  // agg out bf16
    float* adstA  = (float*)alloc((size_t)N * NHEAD * 4);
    float* adstB  = (float*)alloc((size_t)N * NHEAD * 4);
    int*   deg    = (int*)alloc((size_t)N * 4);
    int*   eoff   = (int*)alloc((size_t)(N + 1) * 4);
    int*   erank  = (int*)alloc((size_t)E * 4);
    int2*  epack  = (int2*)alloc((size_t)E * 8);
    int*   bsum   = (int*)alloc(((size_t)(N + 511) / 512) * 4);
    float* kc     = (float*)alloc(24 * 4);
    int*   gstart = (int*)alloc((NGRAPH + 1) * 4);
    float* gsum   = (float*)alloc(NGRAPH * HCDIM * 4);
    float* wastab = (float*)alloc(32 * 4);
    float* wadtab = (float*)alloc(32 * 4);
    unsigned short* wt2 = (unsigned short*)alloc(WEXT * HCDIM * 2);
    unsigned short* wt3 = (unsigned short*)alloc(WEXT * HCDIM * 2);

    const int NB = (N + 255) / 256;
    const int NB512 = (N + 511) / 512;
    const int EB = (E + 255) / 256;
    const int AGG_BLOCKS = (((N + 3) / 4) * 64 + 255) / 256;   // 4 nodes/wave
    const int GEMM_BLOCKS = (N + 127) / 128;                   // 128 rows per block

    setup0<<<NB, 256, 0, stream>>>(deg, gsum,
                                   w2, w3, wt2, wt3,
                                   we1, ae1, we2, ae2, we3, ae3, kc,
                                   as2, ad2, as3, ad3,
                                   w1, as1, ad1, wastab, wadtab,
                                   batch, gstart, N);
    count_deg<<<EB, 256, 0, stream>>>(dst, deg, erank, E);
    block_sum<<<NB512, 512, 0, stream>>>(deg, bsum, N);
    scan_final2<<<NB512, 512, 0, stream>>>(deg, bsum, NB512, eoff, N);
    scatter_edges<<<EB, 256, 0, stream>>>(src, dst, eattr, eoff, erank, epack, E);

    // layer 1 (no self loops): rank-4 accumulate + epilogue W1 expand -> bf16
    gat_aggregate1<<<AGG_BLOCKS, 256, 0, stream>>>(x, epack, eoff, w1, wastab, wadtab,
                                                   kc + 0, b1, Bbf, N);
    // layer 2: gemm (bf16 MFMA) emits fp8 h2 rows + adst2 (asrc in-register)
    gemm_mfma<<<GEMM_BLOCKS, 256, 0, stream>>>(Bbf, wt2, A8, adstB, N);
    gat_aggregate<<<AGG_BLOCKS, 256, 0, stream>>>(A8, adstB, as2, epack, eoff,
                                                  kc + 8, b2, Bbf, N, 1);
    // layer 3
    gemm_mfma<<<GEMM_BLOCKS, 256, 0, stream>>>(Bbf, wt3, A8, adstA, N);
    gat_aggregate<<<AGG_BLOCKS, 256, 0, stream>>>(A8, adstA, as3, epack, eoff,
                                                  kc + 16, b3, Bbf, N, 1);

    // segmented mean-pool (bf16 in) + MLP head
    pool_seg<<<NGRAPH * 8, 128, 0, stream>>>(Bbf, gstart, gsum);
    mlp_kernel<<<NGRAPH, 64, 0, stream>>>(gsum, gstart, fw1, fb1, fw2, fb2, (float*)d_out);
}

// Round 10
// 300.389 us; speedup vs baseline: 1.1566x; 1.0174x over previous
//
#include <hip/hip_runtime.h>
#include <hip/hip_bf16.h>
#include <math.h>

#define NHEAD 8
#define CDIM 16
#define HCDIM 128
#define NGRAPH 64
#define WEXT 144   // 128 gemm cols + 8 src-coeff cols + 8 dst-coeff cols
#define SWPAD 136  // bf16 W row pad: 68 dwords == 4 mod 32 banks

typedef __attribute__((ext_vector_type(8))) short short8;
typedef __attribute__((ext_vector_type(4))) float f32x4;
typedef __attribute__((ext_vector_type(2))) float f32x2;

static __device__ __forceinline__ unsigned short f2bf(float f) {
    unsigned u = __float_as_uint(f);
    unsigned r = (u + 0x7FFF + ((u >> 16) & 1)) >> 16;   // rne
    return (unsigned short)r;
}
static __device__ __forceinline__ float bf2f(unsigned short s) {
    return __uint_as_float(((unsigned)s) << 16);
}
// encode one float -> fp8 e4m3 byte via HW cvt (RNE)
static __device__ __forceinline__ unsigned char f2fp8(float v) {
    int r = __builtin_amdgcn_cvt_pk_fp8_f32(v, v, 0, false);
    return (unsigned char)(r & 0xff);
}
// decode fp8 byte (in low 8 bits of x) -> float
static __device__ __forceinline__ float fp82f(int x) {
    f32x2 t = __builtin_amdgcn_cvt_pk_f32_fp8(x, false);
    return t[0];
}

// ---------------------------------------------------------------- setup

// merged: zero deg/gsum + kcoef + graph_bounds + bf16 extended weight build
// + layer-1 coeff tables was1/wad1 [4][8]   (weights stay BF16: systematic
// error does not wash in the pool average — R9 lesson)
__global__ void setup0(int* __restrict__ deg,
                       float* __restrict__ gsum,
                       const float* __restrict__ w2, const float* __restrict__ w3,
                       unsigned short* __restrict__ wt2, unsigned short* __restrict__ wt3,
                       const float* __restrict__ we1, const float* __restrict__ ae1,
                       const float* __restrict__ we2, const float* __restrict__ ae2,
                       const float* __restrict__ we3, const float* __restrict__ ae3,
                       float* __restrict__ kc,
                       const float* __restrict__ as2, const float* __restrict__ ad2,
                       const float* __restrict__ as3, const float* __restrict__ ad3,
                       const float* __restrict__ w1,
                       const float* __restrict__ as1, const float* __restrict__ ad1,
                       float* __restrict__ wastab, float* __restrict__ wadtab,
                       const int* __restrict__ batch, int* __restrict__ gstart, int n) {
    int i = blockIdx.x * 256 + threadIdx.x;
    if (i < n) deg[i] = 0;
    if (i < NGRAPH * HCDIM) gsum[i] = 0.f;
    if (i < WEXT * HCDIM) {
        int nn = i >> 7, k = i & 127;
        float v2, v3;
        if (nn < HCDIM) {
            v2 = w2[k * HCDIM + nn];
            v3 = w3[k * HCDIM + nn];
        } else if (nn < HCDIM + NHEAD) {
            int h = nn - HCDIM;
            float s2 = 0.f, s3 = 0.f;
#pragma unroll
            for (int c = 0; c < CDIM; ++c) {
                s2 += w2[k * HCDIM + h * CDIM + c] * as2[h * CDIM + c];
                s3 += w3[k * HCDIM + h * CDIM + c] * as3[h * CDIM + c];
            }
            v2 = s2; v3 = s3;
        } else {
            int h = nn - HCDIM - NHEAD;
            float s2 = 0.f, s3 = 0.f;
#pragma unroll
            for (int c = 0; c < CDIM; ++c) {
                s2 += w2[k * HCDIM + h * CDIM + c] * ad2[h * CDIM + c];
                s3 += w3[k * HCDIM + h * CDIM + c] * ad3[h * CDIM + c];
            }
            v2 = s2; v3 = s3;
        }
        wt2[nn * HCDIM + k] = f2bf(v2);
        wt3[nn * HCDIM + k] = f2bf(v3);
    }
    if (i < 24) {
        int l = i >> 3, h = i & 7;
        const float* we = (l == 0) ? we1 : ((l == 1) ? we2 : we3);
        const float* ae = (l == 0) ? ae1 : ((l == 1) ? ae2 : ae3);
        float s = 0.f;
        for (int c = 0; c < CDIM; ++c) s += we[h * CDIM + c] * ae[h * CDIM + c];
        kc[i] = s;
    }
    if (i >= 18560 && i <= 18560 + NGRAPH) {   // graph bounds, disjoint range
        int g = i - 18560;
        int lo = 0, hi = n;
        while (lo < hi) {
            int mid = (lo + hi) >> 1;
            if (batch[mid] < g) lo = mid + 1; else hi = mid;
        }
        gstart[g] = lo;
    }
    if (i >= 18700 && i < 18732) {   // layer-1 coeff tables [4][8]
        int t = i - 18700;
        int k = t >> 3, h = t & 7;
        float ss = 0.f, sd = 0.f;
#pragma unroll
        for (int c = 0; c < CDIM; ++c) {
            ss += w1[k * HCDIM + h * CDIM + c] * as1[h * CDIM + c];
            sd += w1[k * HCDIM + h * CDIM + c] * ad1[h * CDIM + c];
        }
        wastab[t] = ss;
        wadtab[t] = sd;
    }
}

// counts degree AND records each edge's within-dst rank so scatter is atomic-free.
__global__ void count_deg(const int* __restrict__ dst, int* __restrict__ deg,
                          int* __restrict__ erank, int E) {
    int e = blockIdx.x * 256 + threadIdx.x;
    if (e >= E) return;
    erank[e] = atomicAdd(&deg[dst[e]], 1);
}

__global__ __launch_bounds__(512) void block_sum(const int* __restrict__ deg,
                                                 int* __restrict__ bsum, int n) {
    __shared__ int s[512];
    int i = blockIdx.x * 512 + threadIdx.x;
    s[threadIdx.x] = (i < n) ? deg[i] : 0;
    __syncthreads();
    for (int off = 256; off > 0; off >>= 1) {
        if (threadIdx.x < off) s[threadIdx.x] += s[threadIdx.x + off];
        __syncthreads();
    }
    if (threadIdx.x == 0) bsum[blockIdx.x] = s[0];
}

// fused: every block scans the (<=512-entry) bsum array in LDS AND its own
// 512-entry deg slice, producing eoff directly.
__global__ __launch_bounds__(512) void scan_final2(const int* __restrict__ deg,
                                                   const int* __restrict__ bsum, int nb,
                                                   int* __restrict__ eoff, int n) {
    __shared__ int ls[512];
    __shared__ int s[512];
    const int t = threadIdx.x;
    ls[t] = (t < nb) ? bsum[t] : 0;
    int i = blockIdx.x * 512 + t;
    s[t] = (i < n) ? deg[i] : 0;
    __syncthreads();
    for (int off = 1; off < 512; off <<= 1) {
        int a1 = (t >= off) ? ls[t - off] : 0;
        int a2 = (t >= off) ? s[t - off] : 0;
        __syncthreads();
        ls[t] += a1; s[t] += a2;
        __syncthreads();
    }
    int base = (blockIdx.x > 0) ? ls[blockIdx.x - 1] : 0;   // exclusive block base
    if (i < n) eoff[i + 1] = base + s[t];
    if (i == 0) eoff[0] = 0;
}

// atomic-free scatter: position = eoff[dst] + precomputed rank.
// epack is 4B/edge: src node id in bits [0,24), fp8(eattr) in bits [24,32).
__global__ void scatter_edges(const int* __restrict__ src, const int* __restrict__ dst,
                              const float* __restrict__ eattr,
                              const int* __restrict__ eoff,
                              const int* __restrict__ erank,
                              unsigned* __restrict__ epack, int E) {
    int e = blockIdx.x * 256 + threadIdx.x;
    if (e >= E) return;
    int p = eoff[dst[e]] + erank[e];
    epack[p] = ((unsigned)src[e] & 0xFFFFFFu) | ((unsigned)f2fp8(eattr[e]) << 24);
}

// ---------------------------------------------------------------- layer-1 aggregate

// h is rank-4:  Σ_e w_e·(x_e@W1) = (Σ_e w_e·x_e)@W1.
// FOUR nodes per wave (16 lanes x 8 channels each); prefetched epack.
// Output: fp8 rows (per-node error, washes; gemm re-expands to bf16).
__global__ __launch_bounds__(256) void gat_aggregate1(
    const float* __restrict__ x,        // [n,4]
    const unsigned* __restrict__ epack, // [E] dst-sorted packed {src24, fp8 ea}
    const int*   __restrict__ eoff,     // [n+1]
    const float* __restrict__ w1,       // [4][128]
    const float* __restrict__ wastab,   // [4][8]
    const float* __restrict__ wadtab,   // [4][8]
    const float* __restrict__ kc,       // [8]
    const float* __restrict__ bias,     // [128]
    unsigned char* __restrict__ out8,   // [n,128] fp8
    int n) {
    const int lane = threadIdx.x & 63;
    const int l16 = lane & 15;
    int nid = ((blockIdx.x * 256 + threadIdx.x) >> 6) * 4 + (lane >> 4);
    if (nid >= n) return;
    const int h = l16 >> 1;           // 2 lanes per head
    const int c0 = l16 * 8;           // 8 contiguous channels per lane

    float was0 = wastab[0 * NHEAD + h], was1_ = wastab[1 * NHEAD + h];
    float was2 = wastab[2 * NHEAD + h], was3 = wastab[3 * NHEAD + h];
    float wad0 = wadtab[0 * NHEAD + h], wad1_ = wadtab[1 * NHEAD + h];
    float wad2 = wadtab[2 * NHEAD + h], wad3 = wadtab[3 * NHEAD + h];

    f32x4 xd = *(const f32x4*)(x + (((unsigned)nid) << 2));
    const float adst_h = xd[0] * wad0 + xd[1] * wad1_ + xd[2] * wad2 + xd[3] * wad3;
    const float k_h = kc[h];
    const int e0 = eoff[nid], e1 = eoff[nid + 1];

    float den = 0.f;
    f32x4 acc4 = (f32x4){0.f, 0.f, 0.f, 0.f};   // Σ w_e · x_e

    if (e0 < e1) {
        unsigned ep[4];
#pragma unroll
        for (int j = 0; j < 4; ++j) {
            int idx = e0 + j; idx = (idx < e1) ? idx : (e1 - 1);
            ep[j] = epack[idx];
        }
        for (int base = e0; base < e1; base += 4) {
            unsigned epn[4];
#pragma unroll
            for (int j = 0; j < 4; ++j) {        // prefetch next group (clamped)
                int idx = base + 4 + j; idx = (idx < e1) ? idx : (e1 - 1);
                epn[j] = epack[idx];
            }
            f32x4 xs[4];
#pragma unroll
            for (int j = 0; j < 4; ++j)
                xs[j] = *(const f32x4*)(x + ((ep[j] & 0xFFFFFFu) << 2));
#pragma unroll
            for (int j = 0; j < 4; ++j) {
                bool valid = (base + j < e1);
                float as_e = xs[j][0] * was0 + xs[j][1] * was1_ +
                             xs[j][2] * was2 + xs[j][3] * was3;
                float ea = fp82f((int)(ep[j] >> 24));
                float a = as_e + adst_h + ea * k_h;
                a = (a > 0.f) ? a : 0.2f * a;
                float w = valid ? __expf(a) : 0.f;
                den += w;
                acc4 += xs[j] * w;               // 2x v_pk_fma_f32
            }
#pragma unroll
            for (int j = 0; j < 4; ++j) ep[j] = epn[j];
        }
    }

    // epilogue: expand acc4 through 8 W1 columns (once per node) -> fp8
    float inv = 1.f / (den + 1e-16f);
    float oc[8];
#pragma unroll
    for (int c = 0; c < 8; ++c) {
        float v = acc4[0] * w1[0 * HCDIM + c0 + c] + acc4[1] * w1[1 * HCDIM + c0 + c] +
                  acc4[2] * w1[2 * HCDIM + c0 + c] + acc4[3] * w1[3 * HCDIM + c0 + c];
        oc[c] = fmaxf(v * inv + bias[c0 + c], 0.f);
    }
    int w0 = __builtin_amdgcn_cvt_pk_fp8_f32(oc[0], oc[1], 0, false);
    w0 = __builtin_amdgcn_cvt_pk_fp8_f32(oc[2], oc[3], w0, true);
    int w1p = __builtin_amdgcn_cvt_pk_fp8_f32(oc[4], oc[5], 0, false);
    w1p = __builtin_amdgcn_cvt_pk_fp8_f32(oc[6], oc[7], w1p, true);
    *(uint2*)(out8 + ((long)nid << 7) + c0) = make_uint2((unsigned)w0, (unsigned)w1p);
}

// ---------------------------------------------------------------- gemm

// layers 2/3: [n,128] @ [128,144]. A rows arrive as fp8 (half read traffic)
// and are expanded IN-REGISTER to bf16 (exact: e4m3 subset of bf16); weights
// stay bf16 in padded LDS; MFMA is the proven bf16 16x16x32 path.
// cols 0..127 -> Y8 fp8 (gather payload); dst-coeff cols -> adst fp32.
__global__ __launch_bounds__(256) void gemm_mfma(const unsigned char* __restrict__ A8,
                                                 const unsigned short* __restrict__ Wt,
                                                 unsigned char* __restrict__ Y8,
                                                 float* __restrict__ adstn, int n) {
    __shared__ unsigned short sW[WEXT][SWPAD];
    for (int i = threadIdx.x; i < WEXT * 16; i += 256) {
        int r = i >> 4, c = (i & 15) << 3;
        *(short8*)&sW[r][c] = *(const short8*)(Wt + r * HCDIM + c);
    }
    __syncthreads();

    const int wave = threadIdx.x >> 6;
    const int lane = threadIdx.x & 63;
    const int quad = lane >> 4;
    const int l16  = lane & 15;
    const int rowbase = (blockIdx.x * 8 + wave * 2) * 16;

    f32x4 acc[2][9];
#pragma unroll
    for (int r = 0; r < 2; ++r)
#pragma unroll
        for (int t = 0; t < 9; ++t) acc[r][t] = (f32x4){0.f, 0.f, 0.f, 0.f};

#pragma unroll
    for (int kb = 0; kb < HCDIM; kb += 32) {
        short8 a[2];
#pragma unroll
        for (int r = 0; r < 2; ++r) {
            int row = rowbase + r * 16 + l16;
            row = (row < n) ? row : (n - 1);
            uint2 a8v = *(const uint2*)(A8 + (long)row * HCDIM + kb + quad * 8);
            f32x2 q0 = __builtin_amdgcn_cvt_pk_f32_fp8((int)a8v.x, false);
            f32x2 q1 = __builtin_amdgcn_cvt_pk_f32_fp8((int)a8v.x, true);
            f32x2 q2 = __builtin_amdgcn_cvt_pk_f32_fp8((int)a8v.y, false);
            f32x2 q3 = __builtin_amdgcn_cvt_pk_f32_fp8((int)a8v.y, true);
            a[r][0] = (short)f2bf(q0[0]); a[r][1] = (short)f2bf(q0[1]);
            a[r][2] = (short)f2bf(q1[0]); a[r][3] = (short)f2bf(q1[1]);
            a[r][4] = (short)f2bf(q2[0]); a[r][5] = (short)f2bf(q2[1]);
            a[r][6] = (short)f2bf(q3[0]); a[r][7] = (short)f2bf(q3[1]);
        }
#pragma unroll
        for (int nt = 0; nt < 9; ++nt) {
            short8 b = *(const short8*)(&sW[nt * 16 + l16][kb + quad * 8]);
#pragma unroll
            for (int r = 0; r < 2; ++r)
                acc[r][nt] = __builtin_amdgcn_mfma_f32_16x16x32_bf16(a[r], b, acc[r][nt], 0, 0, 0);
        }
    }

    // C/D layout: col = l16, row_local = quad*4 + reg
#pragma unroll
    for (int r = 0; r < 2; ++r) {
#pragma unroll
        for (int reg = 0; reg < 4; ++reg) {
            int row = rowbase + r * 16 + quad * 4 + reg;
            if (row < n) {
                unsigned char* yp = Y8 + (long)row * HCDIM + l16;
#pragma unroll
                for (int nt = 0; nt < 8; ++nt) yp[nt * 16] = f2fp8(acc[r][nt][reg]);
                if (l16 >= 8) adstn[row * NHEAD + (l16 - 8)] = acc[r][8][reg];
            }
        }
    }
}

// ---------------------------------------------------------------- aggregate (layers 2/3)

// FOUR nodes per wave (16 lanes x 8 fp8 channels each); single pass. Gather
// is 8B/lane (fp8 row = 128B = 2 cachelines/edge). Src coeff computed
// in-register. Output: fp8 (layer-2, feeds gemm3) or bf16 (layer-3 -> pool).
__global__ __launch_bounds__(256) void gat_aggregate(
    const unsigned char* __restrict__ h8, // [n,128] fp8 e4m3
    const float* __restrict__ adst,     // [n,8]
    const float* __restrict__ asw,      // [8][16] this layer's att_src (fp32)
    const unsigned* __restrict__ epack, // [E] dst-sorted packed {src24, fp8 ea}
    const int*   __restrict__ eoff,     // [n+1]
    const float* __restrict__ kc,       // [8] this layer
    const float* __restrict__ bias,     // [128]
    void* __restrict__ out,             // fp8 [n,128] or bf16 [n,128]
    int n, int out_fp8) {
    const int lane = threadIdx.x & 63;
    const int l16 = lane & 15;
    int nid = ((blockIdx.x * 256 + threadIdx.x) >> 6) * 4 + (lane >> 4);
    if (nid >= n) return;
    const int h = l16 >> 1;           // 2 lanes per head
    const int c0 = l16 * 8;           // 8 contiguous channels per lane (byte off)

    // this lane's 8 att_src coeffs (channel-within-head = (l16&1)*8 + k)
    const float* asrow = asw + h * CDIM + (l16 & 1) * 8;
    const f32x2 wp0 = *(const f32x2*)(asrow + 0);
    const f32x2 wp1 = *(const f32x2*)(asrow + 2);
    const f32x2 wp2 = *(const f32x2*)(asrow + 4);
    const f32x2 wp3 = *(const f32x2*)(asrow + 6);

    const float adst_h = adst[nid * NHEAD + h];
    const float k_h = kc[h];
    const int e0 = eoff[nid], e1 = eoff[nid + 1];

    float den = 0.f, sume = 0.f;
    f32x2 acc[4];
#pragma unroll
    for (int p = 0; p < 4; ++p) acc[p] = (f32x2){0.f, 0.f};

    if (e0 < e1) {
        unsigned ep[4];
#pragma unroll
        for (int j = 0; j < 4; ++j) {
            int idx = e0 + j; idx = (idx < e1) ? idx : (e1 - 1);
            ep[j] = epack[idx];
        }
        for (int base = e0; base < e1; base += 4) {
            unsigned epn[4];
#pragma unroll
            for (int j = 0; j < 4; ++j) {        // prefetch next group (clamped)
                int idx = base + 4 + j; idx = (idx < e1) ? idx : (e1 - 1);
                epn[j] = epack[idx];
            }
            uint2 hv[4];
#pragma unroll
            for (int j = 0; j < 4; ++j)
                hv[j] = *(const uint2*)(h8 + ((long)(ep[j] & 0xFFFFFFu) << 7) + c0);
#pragma unroll
            for (int j = 0; j < 4; ++j) {
                bool valid = (base + j < e1);
                f32x2 p0 = __builtin_amdgcn_cvt_pk_f32_fp8((int)hv[j].x, false);
                f32x2 p1 = __builtin_amdgcn_cvt_pk_f32_fp8((int)hv[j].x, true);
                f32x2 p2 = __builtin_amdgcn_cvt_pk_f32_fp8((int)hv[j].y, false);
                f32x2 p3 = __builtin_amdgcn_cvt_pk_f32_fp8((int)hv[j].y, true);
                // src-coeff partial dot over this lane's 8 channels
                f32x2 ds = p0 * wp0 + p1 * wp1 + p2 * wp2 + p3 * wp3;
                float part = ds[0] + ds[1];
                float as_e = part + __shfl_xor(part, 1, 64);
                float ea = fp82f((int)(ep[j] >> 24));
                float a = as_e + adst_h + ea * k_h;
                a = (a > 0.f) ? a : 0.2f * a;
                float w = valid ? __expf(a) : 0.f;
                sume += valid ? ea : 0.f;
                den += w;
                acc[0] += p0 * w;   // v_pk_fma_f32
                acc[1] += p1 * w;
                acc[2] += p2 * w;
                acc[3] += p3 * w;
            }
#pragma unroll
            for (int j = 0; j < 4; ++j) ep[j] = epn[j];
        }
    }

    {   // self-loop; attr = mean of incoming eattr
        float fl = sume / fmaxf((float)(e1 - e0), 1.f);
        uint2 hv = *(const uint2*)(h8 + ((long)(unsigned)nid << 7) + c0);
        f32x2 p0 = __builtin_amdgcn_cvt_pk_f32_fp8((int)hv.x, false);
        f32x2 p1 = __builtin_amdgcn_cvt_pk_f32_fp8((int)hv.x, true);
        f32x2 p2 = __builtin_amdgcn_cvt_pk_f32_fp8((int)hv.y, false);
        f32x2 p3 = __builtin_amdgcn_cvt_pk_f32_fp8((int)hv.y, true);
        f32x2 ds = p0 * wp0 + p1 * wp1 + p2 * wp2 + p3 * wp3;
        float part = ds[0] + ds[1];
        float as_self = part + __shfl_xor(part, 1, 64);
        float a = as_self + adst_h + fl * k_h;
        a = (a > 0.f) ? a : 0.2f * a;
        float w = __expf(a);
        den += w;
        acc[0] += p0 * w;
        acc[1] += p1 * w;
        acc[2] += p2 * w;
        acc[3] += p3 * w;
    }

    float inv = 1.f / (den + 1e-16f);
    float oc[8];
#pragma unroll
    for (int c = 0; c < 8; ++c)
        oc[c] = fmaxf(acc[c >> 1][c & 1] * inv + bias[c0 + c], 0.f);
    if (out_fp8) {
        int w0 = __builtin_amdgcn_cvt_pk_fp8_f32(oc[0], oc[1], 0, false);
        w0 = __builtin_amdgcn_cvt_pk_fp8_f32(oc[2], oc[3], w0, true);
        int w1p = __builtin_amdgcn_cvt_pk_fp8_f32(oc[4], oc[5], 0, false);
        w1p = __builtin_amdgcn_cvt_pk_fp8_f32(oc[6], oc[7], w1p, true);
        *(uint2*)((unsigned char*)out + ((long)nid << 7) + c0) =
            make_uint2((unsigned)w0, (unsigned)w1p);
    } else {
        short8 o;
#pragma unroll
        for (int c = 0; c < 8; ++c) o[c] = (short)f2bf(oc[c]);
        *(short8*)((unsigned short*)out + (long)nid * HCDIM + c0) = o;
    }
}

// ---------------------------------------------------------------- pool + MLP

// segmented pool over bf16 h3: block = (graph g, chunk) over the CONTIGUOUS
// row range gstart[g]..gstart[g+1]. One atomic per column per chunk.
__global__ __launch_bounds__(128) void pool_seg(const unsigned short* __restrict__ H,
                                                const int* __restrict__ gstart,
                                                float* __restrict__ gsum) {
    const int c = threadIdx.x;            // 0..127
    const int g = blockIdx.x >> 3;
    const int chunk = blockIdx.x & 7;
    int s0 = gstart[g], s1 = gstart[g + 1];
    int len = s1 - s0;
    if (len <= 0) return;
    int cl = (len + 7) >> 3;
    int i0 = s0 + chunk * cl;
    int i1 = min(i0 + cl, s1);
    if (i0 >= i1) return;
    float acc = 0.f;
    int i = i0;
    for (; i + 4 <= i1; i += 4) {
        float v0 = bf2f(H[(long)i * HCDIM + c]);
        float v1 = bf2f(H[(long)(i + 1) * HCDIM + c]);
        float v2 = bf2f(H[(long)(i + 2) * HCDIM + c]);
        float v3 = bf2f(H[(long)(i + 3) * HCDIM + c]);
        acc += (v0 + v1) + (v2 + v3);
    }
    for (; i < i1; ++i) acc += bf2f(H[(long)i * HCDIM + c]);
    atomicAdd(&gsum[g * HCDIM + c], acc);
}

__global__ __launch_bounds__(64) void mlp_kernel(const float* __restrict__ gsum,
                                                 const int* __restrict__ gstart,
                                                 const float* __restrict__ fw1,
                                                 const float* __restrict__ fb1,
                                                 const float* __restrict__ fw2,
                                                 const float* __restrict__ fb2,
                                                 float* __restrict__ out) {
    const int g = blockIdx.x;
    const int j = threadIdx.x;            // 0..63
    __shared__ float emb[HCDIM];
    __shared__ float gh[64];
    int cnt = gstart[g + 1] - gstart[g];
    float invc = 1.f / fmaxf((float)cnt, 1.f);
    emb[j] = gsum[g * HCDIM + j] * invc;
    emb[j + 64] = gsum[g * HCDIM + 64 + j] * invc;
    __syncthreads();
    float a = fb1[j];
    for (int k = 0; k < HCDIM; ++k) a += emb[k] * fw1[k * 64 + j];
    gh[j] = fmaxf(a, 0.f);
    __syncthreads();
    if (j < 2) {
        float o = fb2[j];
        for (int k = 0; k < 64; ++k) o += gh[k] * fw2[k * 2 + j];
        out[g * 2 + j] = o;
    }
}

// ---------------------------------------------------------------- launcher

extern "C" void kernel_launch(void* const* d_in, const int* in_sizes, int n_in,
                              void* d_out, int out_size, void* d_ws, size_t ws_size,
                              hipStream_t stream) {
    const float* x     = (const float*)d_in[0];
    const int*   eidx  = (const int*)d_in[1];
    const float* eattr = (const float*)d_in[2];
    const int*   batch = (const int*)d_in[3];
    const float* w1  = (const float*)d_in[4];
    const float* as1 = (const float*)d_in[5];
    const float* ad1 = (const float*)d_in[6];
    const float* we1 = (const float*)d_in[7];
    const float* ae1 = (const float*)d_in[8];
    const float* b1  = (const float*)d_in[9];
    const float* w2  = (const float*)d_in[10];
    const float* as2 = (const float*)d_in[11];
    const float* ad2 = (const float*)d_in[12];
    const float* we2 = (const float*)d_in[13];
    const float* ae2 = (const float*)d_in[14];
    const float* b2  = (const float*)d_in[15];
    const float* w3  = (const float*)d_in[16];
    const float* as3 = (const float*)d_in[17];
    const float* ad3 = (const float*)d_in[18];
    const float* we3 = (const float*)d_in[19];
    const float* ae3 = (const float*)d_in[20];
    const float* b3  = (const float*)d_in[21];
    const float* fw1 = (const float*)d_in[22];
    const float* fb1 = (const float*)d_in[23];
    const float* fw2 = (const float*)d_in[24];
    const float* fb2 = (const float*)d_in[25];

    const int N = in_sizes[3];
    const int E = in_sizes[2];
    const int* src = eidx;
    const int* dst = eidx + E;

    // workspace carve
    char* p = (char*)d_ws;
    auto alloc = [&](size_t bytes) {
        void* r = (void*)p;
        p += (bytes + 255) & ~(size_t)255;
        return r;
    };
    unsigned char*  A8  = (unsigned char*)alloc((size_t)N * HCDIM);       // gemm out fp8
    unsigned char*  B8  = (unsigned char*)alloc((size_t)N * HCDIM);       // agg out fp8
    unsigned short* Cbf = (unsigned short*)alloc((size_t)N * HCDIM * 2);  // agg3 out bf16
    float* adstA  = (float*)alloc((size_t)N * NHEAD * 4);
    float* adstB  = (float*)alloc((size_t)N * NHEAD * 4);
    int*   deg    = (int*)alloc((size_t)N * 4);
    int*   eoff   = (int*)alloc((size_t)(N + 1) * 4);
    int*   erank  = (int*)alloc((size_t)E * 4);
    unsigned* epack = (unsigned*)alloc((size_t)E * 4);
    int*   bsum   = (int*)alloc(((size_t)(N + 511) / 512) * 4);
    float* kc     = (float*)alloc(24 * 4);
    int*   gstart = (int*)alloc((NGRAPH + 1) * 4);
    float* gsum   = (float*)alloc(NGRAPH * HCDIM * 4);
    float* wastab = (float*)alloc(32 * 4);
    float* wadtab = (float*)alloc(32 * 4);
    unsigned short* wt2 = (unsigned short*)alloc(WEXT * HCDIM * 2);
    unsigned short* wt3 = (unsigned short*)alloc(WEXT * HCDIM * 2);

    const int NB = (N + 255) / 256;
    const int NB512 = (N + 511) / 512;
    const int EB = (E + 255) / 256;
    const int AGG_BLOCKS = (((N + 3) / 4) * 64 + 255) / 256;   // 4 nodes/wave
    const int GEMM_BLOCKS = (N + 127) / 128;                   // 128 rows per block

    setup0<<<NB, 256, 0, stream>>>(deg, gsum,
                                   w2, w3, wt2, wt3,
                                   we1, ae1, we2, ae2, we3, ae3, kc,
                                   as2, ad2, as3, ad3,
                                   w1, as1, ad1, wastab, wadtab,
                                   batch, gstart, N);
    count_deg<<<EB, 256, 0, stream>>>(dst, deg, erank, E);
    block_sum<<<NB512, 512, 0, stream>>>(deg, bsum, N);
    scan_final2<<<NB512, 512, 0, stream>>>(deg, bsum, NB512, eoff, N);
    scatter_edges<<<EB, 256, 0, stream>>>(src, dst, eattr, eoff, erank, epack, E);

    // layer 1 (no self loops): rank-4 accumulate -> fp8 rows
    gat_aggregate1<<<AGG_BLOCKS, 256, 0, stream>>>(x, epack, eoff, w1, wastab, wadtab,
                                                   kc + 0, b1, B8, N);
    // layer 2: bf16-MFMA gemm (fp8 A expanded in-register) -> fp8 h2 + adst2
    gemm_mfma<<<GEMM_BLOCKS, 256, 0, stream>>>(B8, wt2, A8, adstB, N);
    gat_aggregate<<<AGG_BLOCKS, 256, 0, stream>>>(A8, adstB, as2, epack, eoff,
                                                  kc + 8, b2, (void*)B8, N, 1);
    // layer 3: same gemm; agg3 writes bf16 for the pool
    gemm_mfma<<<GEMM_BLOCKS, 256, 0, stream>>>(B8, wt3, A8, adstA, N);
    gat_aggregate<<<AGG_BLOCKS, 256, 0, stream>>>(A8, adstA, as3, epack, eoff,
                                                  kc + 16, b3, (void*)Cbf, N, 0);

    // segmented mean-pool (bf16 in) + MLP head
    pool_seg<<<NGRAPH * 8, 128, 0, stream>>>(Cbf, gstart, gsum);
    mlp_kernel<<<NGRAPH, 64, 0, stream>>>(gsum, gstart, fw1, fb1, fw2, fb2, (float*)d_out);
}